// Round 8
// baseline (73.873 us; speedup 1.0000x reference)
//
#include <hip/hip_runtime.h>

constexpr int NPIX  = 1 << 20;      // 1024*1024 pixels
constexpr int NCLS  = 21;
constexpr int NBINS = 480;          // linear bins over [0,8): width = 1.67e-2
constexpr float RANGE = 8.0f;
constexpr float BIN_SCALE = NBINS / RANGE;   // 60
constexpr int NCHUNK = 512;
constexpr int CHUNK_PIX = NPIX / NCHUNK;     // 2048 pixels = 512 quads
constexpr int BLK = 512;                     // 1 quad per thread

typedef int   iv4 __attribute__((ext_vector_type(4)));
typedef float fv4 __attribute__((ext_vector_type(4)));

// ---------------------------------------------------------------------------
// 1) FUSED argmax + 21-class LDS histograms. LDS = 21*480*4 = 39.4 KB ->
//    4 blocks/CU = 32 waves/CU (the occupancy cap). Register-staged loads.
//    u32 bin packs (n | n_fg<<16); chunk = 2048 pixels so both fit u16.
// ---------------------------------------------------------------------------
__global__ void __launch_bounds__(BLK, 8)
k_fused(const iv4* __restrict__ label4, const fv4* __restrict__ pred4,
        unsigned int* __restrict__ part) {
    __shared__ unsigned int sh[NCLS * NBINS];          // 39.375 KB
    const int chunk = blockIdx.x;
    const int t     = threadIdx.x;

    {   // zero LDS (vectorized)
        uint4* s4 = (uint4*)sh;
        for (int b = t; b < NCLS * NBINS / 4; b += BLK)
            s4[b] = make_uint4(0u, 0u, 0u, 0u);
    }
    __syncthreads();

    const int q = chunk * (CHUNK_PIX / 4) + t;         // this thread's quad

    // ---- stage all 21 label loads (independent, all in flight)
    iv4 lv[NCLS];
    #pragma unroll
    for (int c = 0; c < NCLS; ++c)
        lv[c] = label4[(size_t)c * (NPIX / 4) + q];

    // ---- register-only argmax (strict > keeps FIRST max, like jnp.argmax)
    int bx = 0, by = 0, bz = 0, bw = 0;
    iv4 best = lv[0];
    #pragma unroll
    for (int c = 1; c < NCLS; ++c) {
        if (lv[c].x > best.x) { best.x = lv[c].x; bx = c; }
        if (lv[c].y > best.y) { best.y = lv[c].y; by = c; }
        if (lv[c].z > best.z) { best.z = lv[c].z; bz = c; }
        if (lv[c].w > best.w) { best.w = lv[c].w; bw = c; }
    }

    // ---- stage all 21 pred loads (independent, all in flight)
    fv4 pv[NCLS];
    #pragma unroll
    for (int c = 0; c < NCLS; ++c)
        pv[c] = pred4[(size_t)c * (NPIX / 4) + q];

    // ---- histogram
    #pragma unroll
    for (int c = 0; c < NCLS; ++c) {
        unsigned int* shc = sh + c * NBINS;
        {
            unsigned int fg = (bx == c) ? 1u : 0u;
            float e = fabsf((float)fg - pv[c].x);
            int bin = (int)(e * BIN_SCALE); bin = bin < NBINS - 1 ? bin : NBINS - 1;
            atomicAdd(&shc[bin], 1u | (fg << 16));
        }
        {
            unsigned int fg = (by == c) ? 1u : 0u;
            float e = fabsf((float)fg - pv[c].y);
            int bin = (int)(e * BIN_SCALE); bin = bin < NBINS - 1 ? bin : NBINS - 1;
            atomicAdd(&shc[bin], 1u | (fg << 16));
        }
        {
            unsigned int fg = (bz == c) ? 1u : 0u;
            float e = fabsf((float)fg - pv[c].z);
            int bin = (int)(e * BIN_SCALE); bin = bin < NBINS - 1 ? bin : NBINS - 1;
            atomicAdd(&shc[bin], 1u | (fg << 16));
        }
        {
            unsigned int fg = (bw == c) ? 1u : 0u;
            float e = fabsf((float)fg - pv[c].w);
            int bin = (int)(e * BIN_SCALE); bin = bin < NBINS - 1 ? bin : NBINS - 1;
            atomicAdd(&shc[bin], 1u | (fg << 16));
        }
    }
    __syncthreads();

    // ---- flush: block-contiguous, coalesced 16B stores
    uint4* dst = (uint4*)(part + (size_t)chunk * NCLS * NBINS);
    const uint4* src = (const uint4*)sh;
    for (int b = t; b < NCLS * NBINS / 4; b += BLK) dst[b] = src[b];
}

// ---------------------------------------------------------------------------
// 2) FUSED merge + scan: one block per class. Merge the class's bin stripe
//    across all 512 chunk partials (coalesced), then shuffle-scan in-block.
//    Lovasz loss via j = i/(G+i-F); thread t owns descending rank t.
// ---------------------------------------------------------------------------
__global__ void __launch_bounds__(512)
k_mergescan(const unsigned int* __restrict__ part, double* __restrict__ losses) {
    const int c    = blockIdx.x;
    const int t    = threadIdx.x;
    const int lane = t & 63;
    const int wv   = t >> 6;                           // 8 waves

    // rank t: 0 = largest-error bin
    const int bin = NBINS - 1 - t;                     // valid when t < NBINS
    unsigned int tn = 0, tf = 0;
    if (t < NBINS) {
        const unsigned int* p = part + (size_t)c * NBINS + bin;
        #pragma unroll 8
        for (int k = 0; k < NCHUNK; ++k) {
            unsigned int v = p[(size_t)k * (NCLS * NBINS)];
            tn += v & 0xFFFFu;
            tf += v >> 16;
        }
    }

    // wave-inclusive scan of (tn, tf)
    unsigned int in_ = tn, if_ = tf;
    #pragma unroll
    for (int off = 1; off < 64; off <<= 1) {
        unsigned int an = __shfl_up(in_, off, 64);
        unsigned int af = __shfl_up(if_, off, 64);
        if (lane >= off) { in_ += an; if_ += af; }
    }

    __shared__ unsigned int swn[8], swf[8];
    if (lane == 63) { swn[wv] = in_; swf[wv] = if_; }
    __syncthreads();

    if (wv == 0 && lane < 8) {                         // scan the 8 wave totals
        unsigned int a = swn[lane], b = swf[lane];
        #pragma unroll
        for (int off = 1; off < 8; off <<= 1) {
            unsigned int an = __shfl_up(a, off, 64);
            unsigned int af = __shfl_up(b, off, 64);
            if (lane >= off) { a += an; b += af; }
        }
        swn[lane] = a; swf[lane] = b;                  // inclusive wave prefixes
    }
    __syncthreads();

    const unsigned int G = swf[7];                     // total foreground count
    unsigned int i = in_ - tn + (wv ? swn[wv - 1] : 0u);   // exclusive prefix
    unsigned int F = if_ - tf + (wv ? swf[wv - 1] : 0u);

    double acc = 0.0;
    if (tn) {
        double jprev = (i > 0) ? (double)i / (double)(G + i - F) : 0.0;
        unsigned int i2 = i + tn, F2 = F + tf;
        double jhi = (double)i2 / (double)(G + i2 - F2);
        acc = ((bin + 0.5) * (double)(RANGE / NBINS)) * (jhi - jprev);
    }

    // block reduce
    #pragma unroll
    for (int off = 32; off > 0; off >>= 1) acc += __shfl_down(acc, off, 64);
    __shared__ double sd[8];
    if (lane == 0) sd[wv] = acc;
    __syncthreads();
    if (t == 0) {
        double s = 0.0;
        #pragma unroll
        for (int k = 0; k < 8; ++k) s += sd[k];
        losses[c] = s;
    }
}

// ---------------------------------------------------------------------------
// 3) mean over classes
// ---------------------------------------------------------------------------
__global__ void k_final(const double* __restrict__ losses, float* __restrict__ out) {
    if (threadIdx.x == 0 && blockIdx.x == 0) {
        double s = 0.0;
        for (int c = 0; c < NCLS; ++c) s += losses[c];
        out[0] = (float)(s / NCLS);
    }
}

extern "C" void kernel_launch(void* const* d_in, const int* in_sizes, int n_in,
                              void* d_out, int out_size, void* d_ws, size_t ws_size,
                              hipStream_t stream) {
    const float* pred  = (const float*)d_in[0];
    const int*   label = (const int*)d_in[1];
    float* out = (float*)d_out;

    char* ws = (char*)d_ws;
    unsigned int* part = (unsigned int*)ws;                      // 20.6 MB
    size_t off = (size_t)NCHUNK * NCLS * NBINS * 4;
    double* losses = (double*)(ws + off);                        // 168 B

    k_fused<<<NCHUNK, BLK, 0, stream>>>((const iv4*)label, (const fv4*)pred, part);
    k_mergescan<<<NCLS, 512, 0, stream>>>(part, losses);
    k_final<<<1, 64, 0, stream>>>(losses, out);
}

// Round 9
// 41.201 us; speedup vs baseline: 1.7930x; 1.7930x over previous
//
#include <hip/hip_runtime.h>

constexpr int NPIX  = 1 << 20;      // 1024*1024 pixels
constexpr int NCLS  = 21;
constexpr int NBINS = 480;          // linear bins over [0,8): width = 1.67e-2
constexpr float RANGE = 8.0f;
constexpr float BIN_SCALE = NBINS / RANGE;   // 60
constexpr int NCHUNK = 256;
constexpr int CHUNK_PIX = NPIX / NCHUNK;     // 4096 pixels = 1024 quads
constexpr int NGRP = 8;                      // merge hierarchy
constexpr int CPG  = NCHUNK / NGRP;          // 32 chunks per group

typedef int   iv4 __attribute__((ext_vector_type(4)));
typedef float fv4 __attribute__((ext_vector_type(4)));

// ---------------------------------------------------------------------------
// 1) FUSED argmax + 21-class LDS histograms (R7 structure, half the bins).
//    LDS = 21*480*4 = 39.4 KB; grid 256 = 1 block/CU (grid-limited).
//    Register-staged loads for MLP. u32 bin packs (n | n_fg<<16);
//    chunk = 4096 pixels so both fields fit u16.
// ---------------------------------------------------------------------------
__global__ void __launch_bounds__(1024, 4)
k_fused(const iv4* __restrict__ label4, const fv4* __restrict__ pred4,
        unsigned int* __restrict__ part) {
    __shared__ unsigned int sh[NCLS * NBINS];          // 39.375 KB
    const int chunk = blockIdx.x;
    const int t     = threadIdx.x;

    {   // zero LDS (vectorized)
        uint4* s4 = (uint4*)sh;
        for (int b = t; b < NCLS * NBINS / 4; b += 1024)
            s4[b] = make_uint4(0u, 0u, 0u, 0u);
    }
    __syncthreads();

    const int q = chunk * (CHUNK_PIX / 4) + t;         // this thread's quad

    // ---- stage all 21 label loads (independent, all in flight)
    iv4 lv[NCLS];
    #pragma unroll
    for (int c = 0; c < NCLS; ++c)
        lv[c] = label4[(size_t)c * (NPIX / 4) + q];

    // ---- register-only argmax (strict > keeps FIRST max, like jnp.argmax)
    int bx = 0, by = 0, bz = 0, bw = 0;
    iv4 best = lv[0];
    #pragma unroll
    for (int c = 1; c < NCLS; ++c) {
        if (lv[c].x > best.x) { best.x = lv[c].x; bx = c; }
        if (lv[c].y > best.y) { best.y = lv[c].y; by = c; }
        if (lv[c].z > best.z) { best.z = lv[c].z; bz = c; }
        if (lv[c].w > best.w) { best.w = lv[c].w; bw = c; }
    }

    // ---- stage all 21 pred loads (independent, all in flight)
    fv4 pv[NCLS];
    #pragma unroll
    for (int c = 0; c < NCLS; ++c)
        pv[c] = pred4[(size_t)c * (NPIX / 4) + q];

    // ---- histogram
    #pragma unroll
    for (int c = 0; c < NCLS; ++c) {
        unsigned int* shc = sh + c * NBINS;
        {
            unsigned int fg = (bx == c) ? 1u : 0u;
            float e = fabsf((float)fg - pv[c].x);
            int bin = (int)(e * BIN_SCALE); bin = bin < NBINS - 1 ? bin : NBINS - 1;
            atomicAdd(&shc[bin], 1u | (fg << 16));
        }
        {
            unsigned int fg = (by == c) ? 1u : 0u;
            float e = fabsf((float)fg - pv[c].y);
            int bin = (int)(e * BIN_SCALE); bin = bin < NBINS - 1 ? bin : NBINS - 1;
            atomicAdd(&shc[bin], 1u | (fg << 16));
        }
        {
            unsigned int fg = (bz == c) ? 1u : 0u;
            float e = fabsf((float)fg - pv[c].z);
            int bin = (int)(e * BIN_SCALE); bin = bin < NBINS - 1 ? bin : NBINS - 1;
            atomicAdd(&shc[bin], 1u | (fg << 16));
        }
        {
            unsigned int fg = (bw == c) ? 1u : 0u;
            float e = fabsf((float)fg - pv[c].w);
            int bin = (int)(e * BIN_SCALE); bin = bin < NBINS - 1 ? bin : NBINS - 1;
            atomicAdd(&shc[bin], 1u | (fg << 16));
        }
    }
    __syncthreads();

    // ---- flush: block-contiguous, coalesced 16B stores
    uint4* dst = (uint4*)(part + (size_t)chunk * NCLS * NBINS);
    const uint4* src = (const uint4*)sh;
    for (int b = t; b < NCLS * NBINS / 4; b += 1024) dst[b] = src[b];
}

// ---------------------------------------------------------------------------
// 2) hierarchical merge: each (bin-block, group) sums 32 chunks -> u64 part2.
//    Block (0,0) thread 0 also zeroes out[0] for k_scanfinal's atomics.
// ---------------------------------------------------------------------------
__global__ void k_merge(const unsigned int* __restrict__ part,
                        unsigned long long* __restrict__ part2,
                        float* __restrict__ out) {
    if (blockIdx.x == 0 && blockIdx.y == 0 && threadIdx.x == 0) out[0] = 0.0f;
    int b = blockIdx.x * blockDim.x + threadIdx.x;     // over NCLS*NBINS
    if (b >= NCLS * NBINS) return;
    int g = blockIdx.y;
    unsigned int n = 0, f = 0;
    for (int k = 0; k < CPG; ++k) {
        unsigned int v = part[(size_t)(g * CPG + k) * (NCLS * NBINS) + b];
        n += v & 0xFFFFu;
        f += v >> 16;
    }
    part2[(size_t)g * (NCLS * NBINS) + b] =
        (unsigned long long)n | ((unsigned long long)f << 32);
}

// ---------------------------------------------------------------------------
// 3) per-class descending scan + Lovasz dot + mean, fused: each class block
//    atomically adds loss_c/NCLS into out[0] (zeroed by k_merge).
// ---------------------------------------------------------------------------
__global__ void __launch_bounds__(512)
k_scanfinal(const unsigned long long* __restrict__ part2, float* __restrict__ out) {
    const int c    = blockIdx.x;
    const int t    = threadIdx.x;
    const int lane = t & 63;
    const int wv   = t >> 6;                           // 8 waves

    // rank t: 0 = largest-error bin. Threads >= NBINS are zero-padding.
    const int bin = NBINS - 1 - t;
    unsigned int tn = 0, tf = 0;
    if (t < NBINS) {
        #pragma unroll
        for (int g = 0; g < NGRP; ++g) {
            unsigned long long v =
                part2[(size_t)g * (NCLS * NBINS) + (size_t)c * NBINS + bin];
            tn += (unsigned int)v;
            tf += (unsigned int)(v >> 32);
        }
    }

    // wave-inclusive scan of (tn, tf)
    unsigned int in_ = tn, if_ = tf;
    #pragma unroll
    for (int off = 1; off < 64; off <<= 1) {
        unsigned int an = __shfl_up(in_, off, 64);
        unsigned int af = __shfl_up(if_, off, 64);
        if (lane >= off) { in_ += an; if_ += af; }
    }

    __shared__ unsigned int swn[8], swf[8];
    if (lane == 63) { swn[wv] = in_; swf[wv] = if_; }
    __syncthreads();

    if (wv == 0 && lane < 8) {                         // scan the 8 wave totals
        unsigned int a = swn[lane], b = swf[lane];
        #pragma unroll
        for (int off = 1; off < 8; off <<= 1) {
            unsigned int an = __shfl_up(a, off, 64);
            unsigned int af = __shfl_up(b, off, 64);
            if (lane >= off) { a += an; b += af; }
        }
        swn[lane] = a; swf[lane] = b;                  // inclusive wave prefixes
    }
    __syncthreads();

    const unsigned int G = swf[7];                     // total foreground count
    unsigned int i = in_ - tn + (wv ? swn[wv - 1] : 0u);   // exclusive prefix
    unsigned int F = if_ - tf + (wv ? swf[wv - 1] : 0u);

    double acc = 0.0;
    if (tn) {
        double jprev = (i > 0) ? (double)i / (double)(G + i - F) : 0.0;
        unsigned int i2 = i + tn, F2 = F + tf;
        double jhi = (double)i2 / (double)(G + i2 - F2);
        acc = ((bin + 0.5) * (double)(RANGE / NBINS)) * (jhi - jprev);
    }

    // block reduce, then one atomicAdd per class
    #pragma unroll
    for (int off = 32; off > 0; off >>= 1) acc += __shfl_down(acc, off, 64);
    __shared__ double sd[8];
    if (lane == 0) sd[wv] = acc;
    __syncthreads();
    if (t == 0) {
        double s = 0.0;
        #pragma unroll
        for (int k = 0; k < 8; ++k) s += sd[k];
        atomicAdd(out, (float)(s / NCLS));
    }
}

extern "C" void kernel_launch(void* const* d_in, const int* in_sizes, int n_in,
                              void* d_out, int out_size, void* d_ws, size_t ws_size,
                              hipStream_t stream) {
    const float* pred  = (const float*)d_in[0];
    const int*   label = (const int*)d_in[1];
    float* out = (float*)d_out;

    char* ws = (char*)d_ws;
    unsigned int* part = (unsigned int*)ws;                      // 10.3 MB
    size_t off = (size_t)NCHUNK * NCLS * NBINS * 4;
    unsigned long long* part2 = (unsigned long long*)(ws + off); // 645 KB

    k_fused<<<NCHUNK, 1024, 0, stream>>>((const iv4*)label, (const fv4*)pred, part);
    dim3 mgrid((NCLS * NBINS + 255) / 256, NGRP);
    k_merge<<<mgrid, 256, 0, stream>>>(part, part2, out);
    k_scanfinal<<<NCLS, 512, 0, stream>>>(part2, out);
}